// Round 8
// baseline (587.464 us; speedup 1.0000x reference)
//
#include <hip/hip_runtime.h>

// EdgeNet: BN -> inputnet MLP -> EdgeConv(linearized) -> mean-pool -> output MLP
// N=50000, E=1.6M, D=13, H=32, G=128. All I/O float32.
// EdgeConv: per-node A = feat@(Wtop-Wbot)+b1, B = feat@Wbot (fp16);
// per-edge h = relu(A[dst]+B[src]); msg = tanh(h@W2+b2) via MFMA f16.
// History: R9 fused-atomic k_edge = 88.5us (atomic floor ~289G dword-RMW/s,
// ~225MB fabric traffic). R11 pipeline = no change. R12 full CSR sort = +178us
// (random 4B scatter dirties full lines -> 100MB). R13/R14 cooperative fusion
// = 6x SLOWER (coop launch degrades memory path) -> abandoned.
// R15: bucketed aggregation (replaces global atomics entirely):
//   k_count: per-block LDS hist of dst>>7 -> global bucket totals
//   k_scanB: 1-block exclusive scan of 391 bucket totals -> base/gcur
//   k_scat:  per-block LDS hist + ONE global reservation per (block,bucket),
//            then LDS-cursor scatter of packed(src|dlo<<16) -> LINE-DENSE writes
//            (~6.4MB payload vs R12's 100MB random-store amplification)
//   k_agg:   block per bucket: MFMA groups of 16 edges, accumulate msg into
//            LDS fp32 via ds atomics (not memory-side RMW), dense Hn writes.
//   Global pk-atomics: 25.6M -> 0. Hn zeroing dropped (k_agg overwrites).

typedef __attribute__((ext_vector_type(4))) float floatx4;
typedef __attribute__((ext_vector_type(8))) short short8;
typedef __attribute__((ext_vector_type(8))) _Float16 half8;
typedef __attribute__((ext_vector_type(2))) __fp16 fp16x2;

__device__ __forceinline__ unsigned short f2bf(float f) {
    unsigned int u = __float_as_uint(f);
    u += 0x7FFFu + ((u >> 16) & 1u);   // RTNE
    return (unsigned short)(u >> 16);
}
__device__ __forceinline__ unsigned short f2h(float f) {
    _Float16 h = (_Float16)f;
    return __builtin_bit_cast(unsigned short, h);
}
__device__ __forceinline__ float h2f(unsigned short u) {
    return (float)__builtin_bit_cast(_Float16, u);
}
__device__ __forceinline__ float fast_tanh(float x) {
    float ax = fminf(fabsf(x), 20.0f);
    float e = __expf(2.0f * ax);
    float r = 1.0f - 2.0f * __builtin_amdgcn_rcpf(e + 1.0f);
    return copysignf(r, x);
}
__device__ __forceinline__ float fast_sigmoid(float x) {
    float xc = fminf(fmaxf(x, -30.f), 30.f);
    return 1.0f / (1.0f + __expf(-xc));
}
__device__ __forceinline__ unsigned int pk_h2(float a, float b) {
    fp16x2 p = __builtin_amdgcn_cvt_pkrtz(a, b);
    return __builtin_bit_cast(unsigned int, p);
}

#define NBLK_STAT 120
#define BKT_BITS 7
#define BKT_SZ 128
#define NPART 256   // blocks for count/scat chunking

// ---------------- K1: BN partial sums + zero gacc/bt ----------------
__global__ __launch_bounds__(256) void k_bnstat(const float* __restrict__ x, int N,
                                                float* __restrict__ part,
                                                float* __restrict__ gacc, int gn,
                                                int* __restrict__ bt, int nb) {
    int tid = blockIdx.x * blockDim.x + threadIdx.x;
    int stride = gridDim.x * blockDim.x;
    for (int i = tid; i < gn; i += stride) gacc[i] = 0.f;
    for (int i = tid; i < nb; i += stride) bt[i] = 0;

    float s[13], q[13];
#pragma unroll
    for (int d = 0; d < 13; d++) { s[d] = 0.f; q[d] = 0.f; }
    for (int n = tid; n < N; n += stride) {
        const float* row = x + (size_t)n * 13;
#pragma unroll
        for (int d = 0; d < 13; d++) { float f = row[d]; s[d] += f; q[d] += f * f; }
    }
#pragma unroll
    for (int d = 0; d < 13; d++) {
        for (int off = 32; off > 0; off >>= 1) {
            s[d] += __shfl_down(s[d], off, 64);
            q[d] += __shfl_down(q[d], off, 64);
        }
    }
    __shared__ float red[4][26];
    int w = threadIdx.x >> 6;
    if ((threadIdx.x & 63) == 0) {
#pragma unroll
        for (int d = 0; d < 13; d++) { red[w][d] = s[d]; red[w][13 + d] = q[d]; }
    }
    __syncthreads();
    if (threadIdx.x < 26) {
        float v = red[0][threadIdx.x] + red[1][threadIdx.x] + red[2][threadIdx.x] + red[3][threadIdx.x];
        int d = threadIdx.x;
        if (d < 13) part[blockIdx.x * 32 + d] = v;
        else        part[NBLK_STAT * 32 + blockIdx.x * 32 + (d - 13)] = v;
    }
}

// ---------------- bucket count ----------------
__global__ __launch_bounds__(256) void k_count(const int* __restrict__ ei, int E, int CH,
                                               int* __restrict__ bt, int nb) {
    __shared__ int h[512];
    const int* dstp = ei + E;
    int tid = threadIdx.x;
    for (int i = tid; i < nb; i += 256) h[i] = 0;
    __syncthreads();
    int e0 = blockIdx.x * CH;
    int e1 = min(e0 + CH, E);
    for (int e = e0 + tid; e < e1; e += 256)
        atomicAdd(&h[dstp[e] >> BKT_BITS], 1);
    __syncthreads();
    for (int i = tid; i < nb; i += 256)
        if (h[i] > 0) atomicAdd(&bt[i], h[i]);
}

// ---------------- bucket scan (one block) ----------------
__global__ __launch_bounds__(512) void k_scanB(const int* __restrict__ bt,
                                               int* __restrict__ base,
                                               int* __restrict__ gcur, int nb, int E) {
    __shared__ int sd[512];
    int t = threadIdx.x;
    int v = (t < nb) ? bt[t] : 0;
    sd[t] = v;
    __syncthreads();
    for (int off = 1; off < 512; off <<= 1) {
        int a = (t >= off) ? sd[t - off] : 0;
        __syncthreads();
        sd[t] += a;
        __syncthreads();
    }
    int excl = sd[t] - v;
    if (t < nb) { base[t] = excl; gcur[t] = excl; }
    if (t == 0) base[nb] = E;
}

// ---------------- bucket scatter (line-dense) ----------------
__global__ __launch_bounds__(256) void k_scat(const int* __restrict__ ei, int E, int CH,
                                              int* __restrict__ gcur,
                                              unsigned* __restrict__ packed, int nb) {
    __shared__ int h[512], cur[512];
    const int* srcp = ei;
    const int* dstp = ei + E;
    int tid = threadIdx.x;
    for (int i = tid; i < nb; i += 256) h[i] = 0;
    __syncthreads();
    int e0 = blockIdx.x * CH;
    int e1 = min(e0 + CH, E);
    for (int e = e0 + tid; e < e1; e += 256)
        atomicAdd(&h[dstp[e] >> BKT_BITS], 1);
    __syncthreads();
    for (int i = tid; i < nb; i += 256)
        cur[i] = (h[i] > 0) ? atomicAdd(&gcur[i], h[i]) : 0;
    __syncthreads();
    for (int e = e0 + tid; e < e1; e += 256) {
        int d = dstp[e];
        int b = d >> BKT_BITS;
        int pos = atomicAdd(&cur[b], 1);
        packed[pos] = (unsigned)srcp[e] | ((unsigned)(d & (BKT_SZ - 1)) << 16);
    }
}

// ---------------- K2: per-node phase ----------------
#define FP 72
#define WP 72
__global__ __launch_bounds__(128) void k_node(
    const float* __restrict__ x, const int* __restrict__ batch,
    const float* __restrict__ bn_g, const float* __restrict__ bn_b,
    const float* __restrict__ in_w1, const float* __restrict__ in_b1,
    const float* __restrict__ in_w2, const float* __restrict__ in_b2,
    const float* __restrict__ conv_w1, const float* __restrict__ conv_b1,
    const float* __restrict__ part,
    unsigned short* __restrict__ A, unsigned short* __restrict__ Bm,
    float* __restrict__ gacc, int N) {
    __shared__ float sW1[13 * 32], sB1[32], sW2[32 * 32], sB2[32];
    __shared__ float sScl[16], sShf[16];
    __shared__ float sRedS[13][8], sRedQ[13][8];
    __shared__ unsigned short sWcatT[128 * WP];
    __shared__ unsigned short sFeat[128 * FP];
    int tid = threadIdx.x;

    for (int i = tid; i < 13 * 32; i += 128) sW1[i] = in_w1[i];
    if (tid < 32) { sB1[tid] = in_b1[tid]; sB2[tid] = in_b2[tid]; }
    for (int i = tid; i < 32 * 32; i += 128) sW2[i] = in_w2[i];
    for (int i = tid; i < 128 * 64; i += 128) {
        int c = i >> 6, k = i & 63;
        float v = 0.f;
        if (k < 45) {
            int cc = c & 63;
            float bot = conv_w1[(45 + k) * 64 + cc];
            v = (c < 64) ? (conv_w1[k * 64 + cc] - bot) : bot;
        }
        sWcatT[c * WP + k] = f2bf(v);
    }
    // parallel reduce of the 120 per-block BN partials
    if (tid < 104) {
        int d = tid >> 3, j = tid & 7;
        float su = 0.f, sq = 0.f;
        for (int b = j; b < NBLK_STAT; b += 8) {
            su += part[b * 32 + d];
            sq += part[NBLK_STAT * 32 + b * 32 + d];
        }
        sRedS[d][j] = su; sRedQ[d][j] = sq;
    }
    __syncthreads();
    if (tid < 13) {
        float su = 0.f, sq = 0.f;
#pragma unroll
        for (int j = 0; j < 8; j++) { su += sRedS[tid][j]; sq += sRedQ[tid][j]; }
        float invN = 1.0f / (float)N;
        float mu = su * invN;
        float var = fmaxf(sq * invN - mu * mu, 0.f);
        float sc = bn_g[tid] / sqrtf(var + 1e-5f);
        sScl[tid] = sc;
        sShf[tid] = bn_b[tid] - mu * sc;
    }
    __syncthreads();

    int n = blockIdx.x * 128 + tid;
    bool valid = (n < N);
    int nl = valid ? n : (N - 1);

    float X[13];
#pragma unroll
    for (int d = 0; d < 13; d++)
        X[d] = x[(size_t)nl * 13 + d] * sScl[d] + sShf[d];
    float h1[32];
#pragma unroll
    for (int j = 0; j < 32; j++) {
        float acc = sB1[j];
#pragma unroll
        for (int d = 0; d < 13; d++) acc += X[d] * sW1[d * 32 + j];
        h1[j] = fmaxf(acc, 0.f);
    }
    float h2[32];
#pragma unroll
    for (int j = 0; j < 32; j++) {
        float acc = sB2[j];
#pragma unroll
        for (int k = 0; k < 32; k++) acc += h1[k] * sW2[k * 32 + j];
        h2[j] = fast_tanh(acc);
    }

    unsigned int fw[16];
#pragma unroll
    for (int i = 0; i < 16; i++) fw[i] = 0;
    if (valid) {
#pragma unroll
        for (int i = 0; i < 16; i++)
            fw[i] = (unsigned)f2bf(h2[2 * i]) | ((unsigned)f2bf(h2[2 * i + 1]) << 16);
    }
    unsigned int xw[7];
#pragma unroll
    for (int i = 0; i < 7; i++) xw[i] = 0;
    if (valid) {
#pragma unroll
        for (int i = 0; i < 6; i++)
            xw[i] = (unsigned)f2bf(X[2 * i]) | ((unsigned)f2bf(X[2 * i + 1]) << 16);
        xw[6] = (unsigned)f2bf(X[12]);
    }
    {
        unsigned short* row = sFeat + tid * FP;
        ((uint4*)row)[0] = make_uint4(fw[0], fw[1], fw[2], fw[3]);
        ((uint4*)row)[1] = make_uint4(fw[4], fw[5], fw[6], fw[7]);
        ((uint4*)row)[2] = make_uint4(fw[8], fw[9], fw[10], fw[11]);
        ((uint4*)row)[3] = make_uint4(fw[12], fw[13], fw[14], fw[15]);
        ((uint4*)row)[4] = make_uint4(xw[0], xw[1], xw[2], xw[3]);
        ((uint4*)row)[5] = make_uint4(xw[4], xw[5], xw[6], 0u);
        ((uint4*)row)[6] = make_uint4(0u, 0u, 0u, 0u);
        ((uint4*)row)[7] = make_uint4(0u, 0u, 0u, 0u);
    }

    {
        int g = valid ? batch[n] : -1;
        unsigned long long uni = __ballot(g == __shfl(g, 0, 64));
        if (uni == ~0ull && g >= 0) {
            float red[14];
#pragma unroll
            for (int d = 0; d < 13; d++) red[d] = X[d];
            red[13] = 1.0f;
#pragma unroll
            for (int d = 0; d < 14; d++)
                for (int off = 32; off > 0; off >>= 1)
                    red[d] += __shfl_down(red[d], off, 64);
            if ((tid & 63) == 0) {
#pragma unroll
                for (int d = 0; d < 13; d++) unsafeAtomicAdd(&gacc[g * 46 + 32 + d], red[d]);
                unsafeAtomicAdd(&gacc[g * 46 + 45], red[13]);
            }
        } else if (valid) {
#pragma unroll
            for (int d = 0; d < 13; d++) unsafeAtomicAdd(&gacc[g * 46 + 32 + d], X[d]);
            unsafeAtomicAdd(&gacc[g * 46 + 45], 1.0f);
        }
    }
    __syncthreads();

    int lane = tid & 63;
    int w = tid >> 6;
    int q = lane >> 4;
    int m = lane & 15;

    short8 wf[2][8];
#pragma unroll
    for (int ks = 0; ks < 2; ks++)
#pragma unroll
        for (int t = 0; t < 8; t++) {
            wf[ks][t] = *(const short8*)(sWcatT + (t * 16 + m) * WP + ks * 32 + q * 8);
        }
    float cb1v[4];
#pragma unroll
    for (int t = 0; t < 4; t++) cb1v[t] = conv_b1[t * 16 + m];

    int base = blockIdx.x * 128 + w * 64;
#pragma unroll
    for (int tile = 0; tile < 4; tile++) {
        const unsigned short* ar = sFeat + (w * 64 + tile * 16 + m) * FP;
        short8 a0 = *(const short8*)(ar + q * 8);
        short8 a1 = *(const short8*)(ar + 32 + q * 8);
        floatx4 c[8];
#pragma unroll
        for (int t = 0; t < 8; t++) {
            floatx4 z = {0.f, 0.f, 0.f, 0.f};
            c[t] = __builtin_amdgcn_mfma_f32_16x16x32_bf16(a0, wf[0][t], z, 0, 0, 0);
            c[t] = __builtin_amdgcn_mfma_f32_16x16x32_bf16(a1, wf[1][t], c[t], 0, 0, 0);
        }
#pragma unroll
        for (int r = 0; r < 4; r++) {
            int row = base + tile * 16 + (q << 2) + r;
            if (row < N) {
#pragma unroll
                for (int t = 0; t < 4; t++)
                    A[(size_t)row * 64 + t * 16 + m] = f2h(c[t][r] + cb1v[t]);
#pragma unroll
                for (int t = 4; t < 8; t++)
                    Bm[(size_t)row * 64 + (t - 4) * 16 + m] = f2h(c[t][r]);
            }
        }
    }
}

// ---------------- K3: bucket aggregation (LDS fp32 atomics, no global RMW) ---
__global__ __launch_bounds__(256) void k_agg(
    const unsigned* __restrict__ packed, const int* __restrict__ base,
    const unsigned short* __restrict__ A, const unsigned short* __restrict__ Bm,
    const float* __restrict__ conv_w2, const float* __restrict__ conv_b2,
    unsigned short* __restrict__ Hn, int N) {
    __shared__ float sAcc[BKT_SZ][32];
    int tid = threadIdx.x;
    for (int i = tid; i < BKT_SZ * 32; i += 256) ((float*)sAcc)[i] = 0.f;

    int bucket = blockIdx.x;
    int n0 = bucket << BKT_BITS;
    int beg = base[bucket], end = base[bucket + 1];
    int cnt = end - beg;

    int lane = tid & 63;
    int w = tid >> 6;
    int q = lane >> 4;
    int m = lane & 15;

    half8 wf[2][2];
#pragma unroll
    for (int s = 0; s < 2; s++)
#pragma unroll
        for (int t = 0; t < 2; t++)
#pragma unroll
            for (int j = 0; j < 8; j++)
                wf[s][t][j] = (_Float16)conv_w2[(s * 32 + q * 8 + j) * 32 + 2 * m + t];
    float cb2a = conv_b2[2 * m];
    float cb2b = conv_b2[2 * m + 1];
    const half8 zero8 = (half8)(_Float16)0.0f;

    __syncthreads();

    int ngrp = (cnt + 15) >> 4;
    for (int g = w; g < ngrp; g += 4) {
        int o = beg + (g << 4);
        unsigned pk = packed[min(o + m, end - 1)];
        int src = (int)(pk & 0xFFFFu);
        int dlo = (int)((pk >> 16) & (BKT_SZ - 1));
        size_t drow = (size_t)(n0 + dlo) * 64;
        uint4 ava = *(const uint4*)(A + drow + q * 8);
        uint4 avb = *(const uint4*)(A + drow + 32 + q * 8);
        uint4 bva = *(const uint4*)(Bm + (size_t)src * 64 + q * 8);
        uint4 bvb = *(const uint4*)(Bm + (size_t)src * 64 + 32 + q * 8);

        half8 ha = __builtin_elementwise_max(
            __builtin_bit_cast(half8, ava) + __builtin_bit_cast(half8, bva), zero8);
        half8 hb = __builtin_elementwise_max(
            __builtin_bit_cast(half8, avb) + __builtin_bit_cast(half8, bvb), zero8);

        floatx4 c0 = {0.f, 0.f, 0.f, 0.f}, c1 = {0.f, 0.f, 0.f, 0.f};
        c0 = __builtin_amdgcn_mfma_f32_16x16x32_f16(ha, wf[0][0], c0, 0, 0, 0);
        c1 = __builtin_amdgcn_mfma_f32_16x16x32_f16(ha, wf[0][1], c1, 0, 0, 0);
        c0 = __builtin_amdgcn_mfma_f32_16x16x32_f16(hb, wf[1][0], c0, 0, 0, 0);
        c1 = __builtin_amdgcn_mfma_f32_16x16x32_f16(hb, wf[1][1], c1, 0, 0, 0);

#pragma unroll
        for (int r = 0; r < 4; r++) {
            int eg = (q << 2) + r;
            int dloe = __shfl(dlo, eg, 64);
            bool valid = ((g << 4) + eg) < cnt;
            float t0 = fast_tanh(c0[r] + cb2a);
            float t1 = fast_tanh(c1[r] + cb2b);
            if (valid) {
                atomicAdd(&sAcc[dloe][2 * m], t0);
                atomicAdd(&sAcc[dloe][2 * m + 1], t1);
            }
        }
    }
    __syncthreads();

    // dense Hn write: 16 half2 per row, coalesced
    for (int i = tid; i < BKT_SZ * 16; i += 256) {
        int row = i >> 4, c2 = i & 15;
        int n = n0 + row;
        if (n < N)
            *(unsigned*)(Hn + (size_t)n * 32 + 2 * c2) =
                pk_h2(sAcc[row][2 * c2], sAcc[row][2 * c2 + 1]);
    }
}

// ---------------- K4: pool f16 Hn into graph accumulators ----------------
__global__ __launch_bounds__(256) void k_pool(const unsigned short* __restrict__ Hn,
                                              const int* __restrict__ batch,
                                              float* __restrict__ gacc, int N) {
    const int NPB = 512;
    int c = threadIdx.x & 31;
    int r = threadIdx.x >> 5;  // 0..7
    int n0 = blockIdx.x * NPB;
    int nend = min(n0 + NPB, N);
    int gcur = -1;
    float acc = 0.f;
    for (int n = n0 + r; n < nend; n += 8) {
        int g = batch[n];
        if (g != gcur) {
            if (gcur >= 0) unsafeAtomicAdd(&gacc[gcur * 46 + c], acc);
            gcur = g; acc = 0.f;
        }
        acc += h2f(Hn[(size_t)n * 32 + c]);
    }
    if (gcur >= 0) unsafeAtomicAdd(&gacc[gcur * 46 + c], acc);
}

// ---------------- K5: output MLP ----------------
__global__ void k_out(const float* __restrict__ gacc,
                      const float* __restrict__ out_w1, const float* __restrict__ out_b1,
                      const float* __restrict__ out_w2, const float* __restrict__ out_b2,
                      float* __restrict__ out, int G) {
    int g = blockIdx.x * blockDim.x + threadIdx.x;
    if (g >= G) return;
    float cnt = fmaxf(gacc[g * 46 + 45], 1.0f);
    float inv = 1.0f / cnt;
    float f[45];
#pragma unroll
    for (int i = 0; i < 45; i++) f[i] = gacc[g * 46 + i] * inv;
    float h[32];
#pragma unroll
    for (int j = 0; j < 32; j++) {
        float acc = out_b1[j];
#pragma unroll
        for (int k = 0; k < 45; k++) acc += f[k] * out_w1[k * 32 + j];
        h[j] = fmaxf(acc, 0.f);
    }
    float o = out_b2[0];
#pragma unroll
    for (int j = 0; j < 32; j++) o += h[j] * out_w2[j];
    out[g] = fast_sigmoid(o);
}

extern "C" void kernel_launch(void* const* d_in, const int* in_sizes, int n_in,
                              void* d_out, int out_size, void* d_ws, size_t ws_size,
                              hipStream_t stream) {
    const float* x      = (const float*)d_in[0];
    const int*   ei     = (const int*)d_in[1];
    const int*   batch  = (const int*)d_in[2];
    const float* bn_g   = (const float*)d_in[3];
    const float* bn_b   = (const float*)d_in[4];
    const float* in_w1  = (const float*)d_in[5];
    const float* in_b1  = (const float*)d_in[6];
    const float* in_w2  = (const float*)d_in[7];
    const float* in_b2  = (const float*)d_in[8];
    const float* cw1    = (const float*)d_in[9];
    const float* cb1    = (const float*)d_in[10];
    const float* cw2    = (const float*)d_in[11];
    const float* cb2    = (const float*)d_in[12];
    const float* ow1    = (const float*)d_in[13];
    const float* ob1    = (const float*)d_in[14];
    const float* ow2    = (const float*)d_in[15];
    const float* ob2    = (const float*)d_in[16];

    int N = in_sizes[0] / 13;
    int E = in_sizes[1] / 2;
    int G = out_size;
    int Npad = (N + 255) & ~255;
    int NB = (N + BKT_SZ - 1) >> BKT_BITS;        // 391 buckets of 128 nodes
    int CH = (E + NPART - 1) / NPART;

    auto al = [](size_t v) { return (v + 255) & ~(size_t)255; };
    char* ws = (char*)d_ws;
    size_t hn_off   = 0;                                  // Hn: f16 [N][32]
    size_t gacc_off = al((size_t)N * 32 * 2);
    size_t part_off = gacc_off + al((size_t)G * 46 * 4);
    size_t a_off    = part_off + al(2 * NBLK_STAT * 32 * 4);
    size_t b_off    = a_off + al((size_t)Npad * 64 * 2);
    size_t bt_off   = b_off + al((size_t)Npad * 64 * 2);
    size_t base_off = bt_off + al((size_t)(NB + 1) * 4);
    size_t gcur_off = base_off + al((size_t)(NB + 1) * 4);
    size_t pk_off   = gcur_off + al((size_t)(NB + 1) * 4);

    unsigned short* Hn = (unsigned short*)(ws + hn_off);
    float* gacc = (float*)(ws + gacc_off);
    float* part = (float*)(ws + part_off);
    unsigned short* A  = (unsigned short*)(ws + a_off);
    unsigned short* Bm = (unsigned short*)(ws + b_off);
    int* bt     = (int*)(ws + bt_off);
    int* baseA  = (int*)(ws + base_off);
    int* gcur   = (int*)(ws + gcur_off);
    unsigned* packed = (unsigned*)(ws + pk_off);

    int gn = G * 46;

    k_bnstat<<<NBLK_STAT, 256, 0, stream>>>(x, N, part, gacc, gn, bt, NB);
    k_count<<<NPART, 256, 0, stream>>>(ei, E, CH, bt, NB);
    k_scanB<<<1, 512, 0, stream>>>(bt, baseA, gcur, NB, E);
    k_scat<<<NPART, 256, 0, stream>>>(ei, E, CH, gcur, packed, NB);
    k_node<<<(N + 127) / 128, 128, 0, stream>>>(x, batch, bn_g, bn_b,
                                                in_w1, in_b1, in_w2, in_b2,
                                                cw1, cb1, part, A, Bm, gacc, N);
    k_agg<<<NB, 256, 0, stream>>>(packed, baseA, A, Bm, cw2, cb2, Hn, N);
    k_pool<<<(N + 511) / 512, 256, 0, stream>>>(Hn, batch, gacc, N);
    k_out<<<1, 128, 0, stream>>>(gacc, ow1, ob1, ow2, ob2, (float*)d_out, G);
}

// Round 9
// 260.649 us; speedup vs baseline: 2.2539x; 2.2539x over previous
//
#include <hip/hip_runtime.h>

// EdgeNet: BN -> inputnet MLP -> EdgeConv(linearized) -> mean-pool -> output MLP
// N=50000, E=1.6M, D=13, H=32, G=128. All I/O float32.
// EdgeConv: per-node A = feat@(Wtop-Wbot)+b1, B = feat@Wbot (fp16);
// per-edge h = relu(A[dst]+B[src]); msg = tanh(h@W2+b2) via MFMA f16,
// scattered to Hn via packed f16 atomics (R9 structure, 88.5us, the proven
// floor: pipeline/CSR/coop-fusion/bucketing all refuted in R11-R15).
// R16: raise TLP of the NON-edge kernels (they sum to ~185us at <2 blocks/CU):
//   - k_node split: k_nodeA = per-node MLP -> feat[Npad][64] bf16 (196 blocks,
//     LDS-staged coalesced stores, zero-fills tail rows);
//     k_nodeB = dense GEMM feat@WcatT -> A|Bm fp16 (784 blocks x 4 waves,
//     no LDS; WcatT bf16 precomputed ONCE into global by k_bnstat).
//   - k_pool: 128 nodes/block -> 391 blocks (was 98).
//   - k_edge: exact R9 kernel (2048 blocks).

typedef __attribute__((ext_vector_type(4))) float floatx4;
typedef __attribute__((ext_vector_type(8))) short short8;
typedef __attribute__((ext_vector_type(8))) _Float16 half8;
typedef __attribute__((ext_vector_type(2))) __fp16 fp16x2;

__device__ __forceinline__ unsigned short f2bf(float f) {
    unsigned int u = __float_as_uint(f);
    u += 0x7FFFu + ((u >> 16) & 1u);   // RTNE
    return (unsigned short)(u >> 16);
}
__device__ __forceinline__ unsigned short f2h(float f) {
    _Float16 h = (_Float16)f;
    return __builtin_bit_cast(unsigned short, h);
}
__device__ __forceinline__ float h2f(unsigned short u) {
    return (float)__builtin_bit_cast(_Float16, u);
}
__device__ __forceinline__ float fast_tanh(float x) {
    float ax = fminf(fabsf(x), 20.0f);
    float e = __expf(2.0f * ax);
    float r = 1.0f - 2.0f * __builtin_amdgcn_rcpf(e + 1.0f);
    return copysignf(r, x);
}
__device__ __forceinline__ float fast_sigmoid(float x) {
    float xc = fminf(fmaxf(x, -30.f), 30.f);
    return 1.0f / (1.0f + __expf(-xc));
}
__device__ __forceinline__ unsigned int pk_h2(float a, float b) {
    fp16x2 p = __builtin_amdgcn_cvt_pkrtz(a, b);
    return __builtin_bit_cast(unsigned int, p);
}
// fire-and-forget packed f16x2 atomic add (memory-side RMW)
__device__ __forceinline__ void atomic_pk_add_f16(unsigned short* addr, unsigned int packed) {
    asm volatile("global_atomic_pk_add_f16 %0, %1, off" :: "v"(addr), "v"(packed) : "memory");
}

#define NBLK_STAT 120

// ---- K1: BN partials + zero Hn/gacc + precompute WcatT (bf16 [128][64]) ----
__global__ __launch_bounds__(256) void k_bnstat(const float* __restrict__ x, int N,
                                                float* __restrict__ part,
                                                uint4* __restrict__ HnZ, int hnq,
                                                float* __restrict__ gacc, int gn,
                                                const float* __restrict__ conv_w1,
                                                unsigned short* __restrict__ wcat) {
    int tid = blockIdx.x * blockDim.x + threadIdx.x;
    int stride = gridDim.x * blockDim.x;
    uint4 z4 = make_uint4(0u, 0u, 0u, 0u);
    for (int i = tid; i < hnq; i += stride) HnZ[i] = z4;
    for (int i = tid; i < gn; i += stride) gacc[i] = 0.f;
    // WcatT[c][k], c=0..127 output col, k=0..63 input: top-bot | bot
    for (int i = tid; i < 128 * 64; i += stride) {
        int c = i >> 6, k = i & 63;
        float v = 0.f;
        if (k < 45) {
            int cc = c & 63;
            float bot = conv_w1[(45 + k) * 64 + cc];
            v = (c < 64) ? (conv_w1[k * 64 + cc] - bot) : bot;
        }
        wcat[i] = f2bf(v);
    }

    float s[13], q[13];
#pragma unroll
    for (int d = 0; d < 13; d++) { s[d] = 0.f; q[d] = 0.f; }
    for (int n = tid; n < N; n += stride) {
        const float* row = x + (size_t)n * 13;
#pragma unroll
        for (int d = 0; d < 13; d++) { float f = row[d]; s[d] += f; q[d] += f * f; }
    }
#pragma unroll
    for (int d = 0; d < 13; d++) {
        for (int off = 32; off > 0; off >>= 1) {
            s[d] += __shfl_down(s[d], off, 64);
            q[d] += __shfl_down(q[d], off, 64);
        }
    }
    __shared__ float red[4][26];
    int w = threadIdx.x >> 6;
    if ((threadIdx.x & 63) == 0) {
#pragma unroll
        for (int d = 0; d < 13; d++) { red[w][d] = s[d]; red[w][13 + d] = q[d]; }
    }
    __syncthreads();
    if (threadIdx.x < 26) {
        float v = red[0][threadIdx.x] + red[1][threadIdx.x] + red[2][threadIdx.x] + red[3][threadIdx.x];
        int d = threadIdx.x;
        if (d < 13) part[blockIdx.x * 32 + d] = v;
        else        part[NBLK_STAT * 32 + blockIdx.x * 32 + (d - 13)] = v;
    }
}

// ---------------- K2a: per-node MLP -> feat (bf16 [Npad][64]) ----------------
__global__ __launch_bounds__(256) void k_nodeA(
    const float* __restrict__ x, const int* __restrict__ batch,
    const float* __restrict__ bn_g, const float* __restrict__ bn_b,
    const float* __restrict__ in_w1, const float* __restrict__ in_b1,
    const float* __restrict__ in_w2, const float* __restrict__ in_b2,
    const float* __restrict__ part,
    unsigned short* __restrict__ feat, float* __restrict__ gacc, int N) {
    __shared__ float sW1[13 * 32], sB1[32], sW2[32 * 32], sB2[32];
    __shared__ float sScl[16], sShf[16];
    __shared__ float sRedS[13][8], sRedQ[13][8];
    __shared__ unsigned short sFeat[256 * 64];
    int tid = threadIdx.x;

    for (int i = tid; i < 13 * 32; i += 256) sW1[i] = in_w1[i];
    if (tid < 32) { sB1[tid] = in_b1[tid]; sB2[tid] = in_b2[tid]; }
    for (int i = tid; i < 32 * 32; i += 256) sW2[i] = in_w2[i];
    if (tid < 104) {
        int d = tid >> 3, j = tid & 7;
        float su = 0.f, sq = 0.f;
        for (int b = j; b < NBLK_STAT; b += 8) {
            su += part[b * 32 + d];
            sq += part[NBLK_STAT * 32 + b * 32 + d];
        }
        sRedS[d][j] = su; sRedQ[d][j] = sq;
    }
    __syncthreads();
    if (tid < 13) {
        float su = 0.f, sq = 0.f;
#pragma unroll
        for (int j = 0; j < 8; j++) { su += sRedS[tid][j]; sq += sRedQ[tid][j]; }
        float invN = 1.0f / (float)N;
        float mu = su * invN;
        float var = fmaxf(sq * invN - mu * mu, 0.f);
        float sc = bn_g[tid] / sqrtf(var + 1e-5f);
        sScl[tid] = sc;
        sShf[tid] = bn_b[tid] - mu * sc;
    }
    __syncthreads();

    int n = blockIdx.x * 256 + tid;
    bool valid = (n < N);
    int nl = valid ? n : (N - 1);

    float X[13];
#pragma unroll
    for (int d = 0; d < 13; d++)
        X[d] = x[(size_t)nl * 13 + d] * sScl[d] + sShf[d];
    float h1[32];
#pragma unroll
    for (int j = 0; j < 32; j++) {
        float acc = sB1[j];
#pragma unroll
        for (int d = 0; d < 13; d++) acc += X[d] * sW1[d * 32 + j];
        h1[j] = fmaxf(acc, 0.f);
    }
    float h2[32];
#pragma unroll
    for (int j = 0; j < 32; j++) {
        float acc = sB2[j];
#pragma unroll
        for (int k = 0; k < 32; k++) acc += h1[k] * sW2[k * 32 + j];
        h2[j] = fast_tanh(acc);
    }

    unsigned int fw[16];
#pragma unroll
    for (int i = 0; i < 16; i++) fw[i] = 0;
    unsigned int xw[7];
#pragma unroll
    for (int i = 0; i < 7; i++) xw[i] = 0;
    if (valid) {
#pragma unroll
        for (int i = 0; i < 16; i++)
            fw[i] = (unsigned)f2bf(h2[2 * i]) | ((unsigned)f2bf(h2[2 * i + 1]) << 16);
#pragma unroll
        for (int i = 0; i < 6; i++)
            xw[i] = (unsigned)f2bf(X[2 * i]) | ((unsigned)f2bf(X[2 * i + 1]) << 16);
        xw[6] = (unsigned)f2bf(X[12]);
    }
    {
        unsigned short* row = sFeat + tid * 64;
        ((uint4*)row)[0] = make_uint4(fw[0], fw[1], fw[2], fw[3]);
        ((uint4*)row)[1] = make_uint4(fw[4], fw[5], fw[6], fw[7]);
        ((uint4*)row)[2] = make_uint4(fw[8], fw[9], fw[10], fw[11]);
        ((uint4*)row)[3] = make_uint4(fw[12], fw[13], fw[14], fw[15]);
        ((uint4*)row)[4] = make_uint4(xw[0], xw[1], xw[2], xw[3]);
        ((uint4*)row)[5] = make_uint4(xw[4], xw[5], xw[6], 0u);
        ((uint4*)row)[6] = make_uint4(0u, 0u, 0u, 0u);
        ((uint4*)row)[7] = make_uint4(0u, 0u, 0u, 0u);
    }

    {
        int g = valid ? batch[n] : -1;
        unsigned long long uni = __ballot(g == __shfl(g, 0, 64));
        if (uni == ~0ull && g >= 0) {
            float red[14];
#pragma unroll
            for (int d = 0; d < 13; d++) red[d] = X[d];
            red[13] = 1.0f;
#pragma unroll
            for (int d = 0; d < 14; d++)
                for (int off = 32; off > 0; off >>= 1)
                    red[d] += __shfl_down(red[d], off, 64);
            if ((tid & 63) == 0) {
#pragma unroll
                for (int d = 0; d < 13; d++) unsafeAtomicAdd(&gacc[g * 46 + 32 + d], red[d]);
                unsafeAtomicAdd(&gacc[g * 46 + 45], red[13]);
            }
        } else if (valid) {
#pragma unroll
            for (int d = 0; d < 13; d++) unsafeAtomicAdd(&gacc[g * 46 + 32 + d], X[d]);
            unsafeAtomicAdd(&gacc[g * 46 + 45], 1.0f);
        }
    }
    __syncthreads();

    // coalesced linear copy: 256*64 ushorts = 2048 uint4
    uint4* dst = (uint4*)(feat + (size_t)blockIdx.x * 256 * 64);
    const uint4* srcq = (const uint4*)sFeat;
#pragma unroll
    for (int j = 0; j < 8; j++) dst[tid + j * 256] = srcq[tid + j * 256];
}

// ---------------- K2b: dense GEMM feat@WcatT -> A|Bm (fp16) ----------------
// 4 waves/block, each wave one 16-row tile; no LDS (feat linear, wcat L2-hot).
__global__ __launch_bounds__(256) void k_nodeB(
    const unsigned short* __restrict__ feat, const unsigned short* __restrict__ wcat,
    const float* __restrict__ conv_b1,
    unsigned short* __restrict__ A, unsigned short* __restrict__ Bm, int N) {
    int tid = threadIdx.x;
    int lane = tid & 63;
    int w = tid >> 6;
    int q = lane >> 4;
    int m = lane & 15;

    short8 wf[2][8];
#pragma unroll
    for (int ks = 0; ks < 2; ks++)
#pragma unroll
        for (int t = 0; t < 8; t++)
            wf[ks][t] = *(const short8*)(wcat + (t * 16 + m) * 64 + ks * 32 + q * 8);
    float cb1v[4];
#pragma unroll
    for (int t = 0; t < 4; t++) cb1v[t] = conv_b1[t * 16 + m];

    int row0 = blockIdx.x * 64 + w * 16;
    const unsigned short* ar = feat + (size_t)(row0 + m) * 64;
    short8 a0 = *(const short8*)(ar + q * 8);
    short8 a1 = *(const short8*)(ar + 32 + q * 8);
    floatx4 c[8];
#pragma unroll
    for (int t = 0; t < 8; t++) {
        floatx4 z = {0.f, 0.f, 0.f, 0.f};
        c[t] = __builtin_amdgcn_mfma_f32_16x16x32_bf16(a0, wf[0][t], z, 0, 0, 0);
        c[t] = __builtin_amdgcn_mfma_f32_16x16x32_bf16(a1, wf[1][t], c[t], 0, 0, 0);
    }
#pragma unroll
    for (int r = 0; r < 4; r++) {
        int row = row0 + (q << 2) + r;
        if (row < N) {
#pragma unroll
            for (int t = 0; t < 4; t++)
                A[(size_t)row * 64 + t * 16 + m] = f2h(c[t][r] + cb1v[t]);
#pragma unroll
            for (int t = 4; t < 8; t++)
                Bm[(size_t)row * 64 + (t - 4) * 16 + m] = f2h(c[t][r]);
        }
    }
}

// ---------------- K3: edge phase (exact R9 kernel) ----------------
__global__ __launch_bounds__(256) void k_edge(
    const int* __restrict__ ei,
    const unsigned short* __restrict__ A, const unsigned short* __restrict__ Bm,
    const float* __restrict__ conv_w2, const float* __restrict__ conv_b2,
    unsigned short* __restrict__ Hn, int E) {
    int lane = threadIdx.x & 63;
    int wid  = blockIdx.x * (blockDim.x >> 6) + (threadIdx.x >> 6);
    int nw   = gridDim.x * (blockDim.x >> 6);
    int q = lane >> 4;
    int m = lane & 15;

    half8 wf[2][2];
#pragma unroll
    for (int s = 0; s < 2; s++)
#pragma unroll
        for (int t = 0; t < 2; t++)
#pragma unroll
            for (int j = 0; j < 8; j++)
                wf[s][t][j] = (_Float16)conv_w2[(s * 32 + q * 8 + j) * 32 + 2 * m + t];
    float cb2a = conv_b2[2 * m];
    float cb2b = conv_b2[2 * m + 1];

    const int* srcp = ei;
    const int* dstp = ei + E;
    int npairs = E >> 5;

    const half8 zero8 = (half8)(_Float16)0.0f;

    for (int p = wid; p < npairs; p += nw) {
        int e0 = p << 5;
        int vd0 = dstp[e0 + m];
        int vs0 = srcp[e0 + m];
        int vd1 = dstp[e0 + 16 + m];
        int vs1 = srcp[e0 + 16 + m];
        uint4 av0a = *(const uint4*)(A  + (size_t)vd0 * 64 + q * 8);
        uint4 av0b = *(const uint4*)(A  + (size_t)vd0 * 64 + 32 + q * 8);
        uint4 bv0a = *(const uint4*)(Bm + (size_t)vs0 * 64 + q * 8);
        uint4 bv0b = *(const uint4*)(Bm + (size_t)vs0 * 64 + 32 + q * 8);
        uint4 av1a = *(const uint4*)(A  + (size_t)vd1 * 64 + q * 8);
        uint4 av1b = *(const uint4*)(A  + (size_t)vd1 * 64 + 32 + q * 8);
        uint4 bv1a = *(const uint4*)(Bm + (size_t)vs1 * 64 + q * 8);
        uint4 bv1b = *(const uint4*)(Bm + (size_t)vs1 * 64 + 32 + q * 8);

        auto mk = [&zero8](uint4 av, uint4 bv) -> half8 {
            half8 a = __builtin_bit_cast(half8, av);
            half8 b = __builtin_bit_cast(half8, bv);
            half8 s = a + b;
            return __builtin_elementwise_max(s, zero8);
        };
        half8 h0a = mk(av0a, bv0a);
        half8 h0b = mk(av0b, bv0b);
        half8 h1a = mk(av1a, bv1a);
        half8 h1b = mk(av1b, bv1b);

        floatx4 c00 = {0.f, 0.f, 0.f, 0.f}, c01 = {0.f, 0.f, 0.f, 0.f};
        floatx4 c10 = {0.f, 0.f, 0.f, 0.f}, c11 = {0.f, 0.f, 0.f, 0.f};
        c00 = __builtin_amdgcn_mfma_f32_16x16x32_f16(h0a, wf[0][0], c00, 0, 0, 0);
        c01 = __builtin_amdgcn_mfma_f32_16x16x32_f16(h0a, wf[0][1], c01, 0, 0, 0);
        c10 = __builtin_amdgcn_mfma_f32_16x16x32_f16(h1a, wf[0][0], c10, 0, 0, 0);
        c11 = __builtin_amdgcn_mfma_f32_16x16x32_f16(h1a, wf[0][1], c11, 0, 0, 0);
        c00 = __builtin_amdgcn_mfma_f32_16x16x32_f16(h0b, wf[1][0], c00, 0, 0, 0);
        c01 = __builtin_amdgcn_mfma_f32_16x16x32_f16(h0b, wf[1][1], c01, 0, 0, 0);
        c10 = __builtin_amdgcn_mfma_f32_16x16x32_f16(h1b, wf[1][0], c10, 0, 0, 0);
        c11 = __builtin_amdgcn_mfma_f32_16x16x32_f16(h1b, wf[1][1], c11, 0, 0, 0);

#pragma unroll
        for (int r = 0; r < 4; r++) {
            int m2 = (q << 2) + r;
            int dd0 = __shfl(vd0, m2, 64);
            int dd1 = __shfl(vd1, m2, 64);
            float o00 = fast_tanh(c00[r] + cb2a);
            float o01 = fast_tanh(c01[r] + cb2b);
            float o10 = fast_tanh(c10[r] + cb2a);
            float o11 = fast_tanh(c11[r] + cb2b);
            atomic_pk_add_f16(Hn + (size_t)dd0 * 32 + 2 * m, pk_h2(o00, o01));
            atomic_pk_add_f16(Hn + (size_t)dd1 * 32 + 2 * m, pk_h2(o10, o11));
        }
    }

    // tail: edges beyond the last full 32-pair (covers E%32)
    int tstart = npairs << 5;
    int tail = E - tstart;
    if (tail && wid == 0 && lane < tail) {
        int e = tstart + lane;
        int vd = dstp[e], vs = srcp[e];
        float h[64];
        for (int k = 0; k < 64; k++) {
            float a = h2f(A[(size_t)vd * 64 + k]);
            float b = h2f(Bm[(size_t)vs * 64 + k]);
            h[k] = fmaxf(a + b, 0.f);
        }
        for (int j = 0; j < 16; j++) {
            float acc0 = conv_b2[2 * j], acc1 = conv_b2[2 * j + 1];
            for (int k = 0; k < 64; k++) {
                acc0 += h[k] * conv_w2[k * 32 + 2 * j];
                acc1 += h[k] * conv_w2[k * 32 + 2 * j + 1];
            }
            atomic_pk_add_f16(Hn + (size_t)vd * 32 + 2 * j, pk_h2(fast_tanh(acc0), fast_tanh(acc1)));
        }
    }
}

// ---------------- K4: pool (128 nodes/block -> 391 blocks) ----------------
__global__ __launch_bounds__(256) void k_pool(const unsigned short* __restrict__ Hn,
                                              const int* __restrict__ batch,
                                              float* __restrict__ gacc, int N) {
    const int NPB = 128;
    int c = threadIdx.x & 31;
    int r = threadIdx.x >> 5;  // 0..7
    int n0 = blockIdx.x * NPB;
    int nend = min(n0 + NPB, N);
    int gcur = -1;
    float acc = 0.f;
    for (int n = n0 + r; n < nend; n += 8) {
        int g = batch[n];
        if (g != gcur) {
            if (gcur >= 0) unsafeAtomicAdd(&gacc[gcur * 46 + c], acc);
            gcur = g; acc = 0.f;
        }
        acc += h2f(Hn[(size_t)n * 32 + c]);
    }
    if (gcur >= 0) unsafeAtomicAdd(&gacc[gcur * 46 + c], acc);
}

// ---------------- K5: output MLP ----------------
__global__ void k_out(const float* __restrict__ gacc,
                      const float* __restrict__ out_w1, const float* __restrict__ out_b1,
                      const float* __restrict__ out_w2, const float* __restrict__ out_b2,
                      float* __restrict__ out, int G) {
    int g = blockIdx.x * blockDim.x + threadIdx.x;
    if (g >= G) return;
    float cnt = fmaxf(gacc[g * 46 + 45], 1.0f);
    float inv = 1.0f / cnt;
    float f[45];
#pragma unroll
    for (int i = 0; i < 45; i++) f[i] = gacc[g * 46 + i] * inv;
    float h[32];
#pragma unroll
    for (int j = 0; j < 32; j++) {
        float acc = out_b1[j];
#pragma unroll
        for (int k = 0; k < 45; k++) acc += f[k] * out_w1[k * 32 + j];
        h[j] = fmaxf(acc, 0.f);
    }
    float o = out_b2[0];
#pragma unroll
    for (int j = 0; j < 32; j++) o += h[j] * out_w2[j];
    out[g] = fast_sigmoid(o);
}

extern "C" void kernel_launch(void* const* d_in, const int* in_sizes, int n_in,
                              void* d_out, int out_size, void* d_ws, size_t ws_size,
                              hipStream_t stream) {
    const float* x      = (const float*)d_in[0];
    const int*   ei     = (const int*)d_in[1];
    const int*   batch  = (const int*)d_in[2];
    const float* bn_g   = (const float*)d_in[3];
    const float* bn_b   = (const float*)d_in[4];
    const float* in_w1  = (const float*)d_in[5];
    const float* in_b1  = (const float*)d_in[6];
    const float* in_w2  = (const float*)d_in[7];
    const float* in_b2  = (const float*)d_in[8];
    const float* cw1    = (const float*)d_in[9];
    const float* cb1    = (const float*)d_in[10];
    const float* cw2    = (const float*)d_in[11];
    const float* cb2    = (const float*)d_in[12];
    const float* ow1    = (const float*)d_in[13];
    const float* ob1    = (const float*)d_in[14];
    const float* ow2    = (const float*)d_in[15];
    const float* ob2    = (const float*)d_in[16];

    int N = in_sizes[0] / 13;
    int E = in_sizes[1] / 2;
    int G = out_size;
    int Npad = (N + 255) & ~255;

    auto al = [](size_t v) { return (v + 255) & ~(size_t)255; };
    char* ws = (char*)d_ws;
    size_t hn_off   = 0;                                  // Hn: f16 [N][32]
    size_t gacc_off = al((size_t)N * 32 * 2);
    size_t part_off = gacc_off + al((size_t)G * 46 * 4);
    size_t a_off    = part_off + al(2 * NBLK_STAT * 32 * 4);
    size_t b_off    = a_off + al((size_t)Npad * 64 * 2);
    size_t ft_off   = b_off + al((size_t)Npad * 64 * 2);
    size_t wc_off   = ft_off + al((size_t)Npad * 64 * 2);

    unsigned short* Hn   = (unsigned short*)(ws + hn_off);
    float* gacc          = (float*)(ws + gacc_off);
    float* part          = (float*)(ws + part_off);
    unsigned short* A    = (unsigned short*)(ws + a_off);
    unsigned short* Bm   = (unsigned short*)(ws + b_off);
    unsigned short* feat = (unsigned short*)(ws + ft_off);
    unsigned short* wcat = (unsigned short*)(ws + wc_off);

    int hnq = (N * 32 * 2) / 16;        // Hn size in uint4s (N*64 bytes)
    int gn  = G * 46;

    k_bnstat<<<NBLK_STAT, 256, 0, stream>>>(x, N, part, (uint4*)Hn, hnq, gacc, gn,
                                            cw1, wcat);
    k_nodeA<<<Npad / 256, 256, 0, stream>>>(x, batch, bn_g, bn_b,
                                            in_w1, in_b1, in_w2, in_b2,
                                            part, feat, gacc, N);
    k_nodeB<<<Npad / 64, 256, 0, stream>>>(feat, wcat, cb1, A, Bm, N);
    k_edge<<<2048, 256, 0, stream>>>(ei, A, Bm, cw2, cb2, Hn, E);
    k_pool<<<(N + 127) / 128, 256, 0, stream>>>(Hn, batch, gacc, N);
    k_out<<<1, 128, 0, stream>>>(gacc, ow1, ob1, ow2, ob2, (float*)d_out, G);
}